// Round 4
// baseline (743.690 us; speedup 1.0000x reference)
//
#include <hip/hip_runtime.h>
#include <hip/hip_bf16.h>

typedef __bf16 bf16;
typedef __bf16 bf16x4 __attribute__((ext_vector_type(4)));
typedef __bf16 bf16x8 __attribute__((ext_vector_type(8)));
typedef float  f32x4  __attribute__((ext_vector_type(4)));

#define MFMA16(a, b, c) __builtin_amdgcn_mfma_f32_16x16x32_bf16((a), (b), (c), 0, 0, 0)

typedef const __attribute__((address_space(1))) void* gptr_t;
typedef __attribute__((address_space(3))) void* sptr_t;

__device__ __forceinline__ void load_lds16(const bf16* g, bf16* l) {
  __builtin_amdgcn_global_load_lds((gptr_t)g, (sptr_t)l, 16, 0, 0);
}

// ---------------- input dtype detector -------------------------------------
__global__ __launch_bounds__(256) void detect_dtype(const unsigned short* __restrict__ w,
                                                    int* __restrict__ flag) {
  __shared__ int cnt[256];
  int c = 0;
#pragma unroll
  for (int k = 0; k < 16; ++k) {
    unsigned short v = w[(threadIdx.x * 16 + k) * 2];
    int e = (v >> 7) & 0xFF;
    c += (e >= 90 && e <= 130) ? 1 : 0;
  }
  cnt[threadIdx.x] = c;
  __syncthreads();
  if (threadIdx.x == 0) {
    int t = 0;
    for (int i = 0; i < 256; ++i) t += cnt[i];
    *flag = (t > 2048) ? 1 : 0;
  }
}

// ---------------- convert x -> bf16 (either source dtype) ------------------
__global__ __launch_bounds__(256) void convert_to_bf16(const void* __restrict__ in,
                                                       bf16* __restrict__ out,
                                                       const int* __restrict__ flag) {
  const int i0 = (blockIdx.x * 256 + threadIdx.x) * 8;
  if (*flag) {
    *(bf16x8*)(out + i0) = *(const bf16x8*)((const bf16*)in + i0);
  } else {
    const float* p = (const float*)in;
    float4 a = *(const float4*)(p + i0);
    float4 b = *(const float4*)(p + i0 + 4);
    bf16x8 v;
    v[0] = (bf16)a.x; v[1] = (bf16)a.y; v[2] = (bf16)a.z; v[3] = (bf16)a.w;
    v[4] = (bf16)b.x; v[5] = (bf16)b.y; v[6] = (bf16)b.z; v[7] = (bf16)b.w;
    *(bf16x8*)(out + i0) = v;
  }
}

// ---------------- transpose+convert: in [R][C] -> out [C][R] bf16 ----------
__global__ __launch_bounds__(256) void transpose_any(const void* __restrict__ in,
                                                     bf16* __restrict__ out,
                                                     const int* __restrict__ flag,
                                                     int R, int C) {
  __shared__ bf16 t[64][65];
  const int c0 = blockIdx.x * 64, r0 = blockIdx.y * 64;
  const int tid = threadIdx.x;
  const int lc = tid & 63, lr4 = tid >> 6;
  if (*flag) {
    const bf16* p = (const bf16*)in;
#pragma unroll
    for (int i = 0; i < 16; ++i) {
      int r = i * 4 + lr4;
      t[r][lc] = p[(size_t)(r0 + r) * C + c0 + lc];
    }
  } else {
    const float* p = (const float*)in;
#pragma unroll
    for (int i = 0; i < 16; ++i) {
      int r = i * 4 + lr4;
      t[r][lc] = (bf16)p[(size_t)(r0 + r) * C + c0 + lc];
    }
  }
  __syncthreads();
#pragma unroll
  for (int i = 0; i < 16; ++i) {
    int r = i * 4 + lr4;
    out[(size_t)(c0 + r) * R + r0 + lc] = t[lc][r];
  }
}

// ---------------- V^T: qkv[b][j][2048 + h*64 + d] -> vt[bh][d][j] ----------
__global__ __launch_bounds__(256) void transpose_v(const bf16* __restrict__ qkv,
                                                   bf16* __restrict__ vt) {
  __shared__ bf16 t[64][65];
  const int bh = blockIdx.y, b = bh >> 4, h = bh & 15;
  const int j0 = blockIdx.x * 64;
  const int tid = threadIdx.x;
  const int lc = tid & 63, lr4 = tid >> 6;
  const bf16* src = qkv + (size_t)b * 2048 * 3072 + 2048 + (size_t)h * 64;
#pragma unroll
  for (int i = 0; i < 16; ++i) {
    int j = i * 4 + lr4;
    t[j][lc] = src[(size_t)(j0 + j) * 3072 + lc];
  }
  __syncthreads();
  bf16* dst = vt + (size_t)bh * 64 * 2048;
#pragma unroll
  for (int i = 0; i < 16; ++i) {
    int d = i * 4 + lr4;
    dst[(size_t)d * 2048 + j0 + lc] = t[lc][d];
  }
}

// ---------------- GEMM: C[M][N] = A[M][K] * Bt[N][K]^T, bf16 in, CT out ----
template <typename CT>
__global__ __launch_bounds__(256) void gemm_bt(const bf16* __restrict__ A,
                                               const bf16* __restrict__ Bt,
                                               CT* __restrict__ C,
                                               int K, int ldc) {
  __shared__ bf16 a_lds[128 * 32];
  __shared__ bf16 b_lds[128 * 32];
  const int tid = threadIdx.x;
  const int w = tid >> 6, lane = tid & 63, l15 = lane & 15, quad = lane >> 4;
  const int wr = w >> 1, wc = w & 1;
  const int m0 = blockIdx.y * 128, n0 = blockIdx.x * 128;

  const f32x4 fz = {0.f, 0.f, 0.f, 0.f};
  f32x4 acc[4][4];
#pragma unroll
  for (int i = 0; i < 4; ++i)
#pragma unroll
    for (int j = 0; j < 4; ++j) acc[i][j] = fz;

  for (int k0 = 0; k0 < K; k0 += 32) {
#pragma unroll
    for (int i = 0; i < 2; ++i) {
      int c = tid + i * 256;
      int r = c >> 2, kk = c & 3;
      load_lds16(A + (size_t)(m0 + r) * K + k0 + kk * 8, &a_lds[c * 8]);
      load_lds16(Bt + (size_t)(n0 + r) * K + k0 + kk * 8, &b_lds[c * 8]);
    }
    __syncthreads();
    bf16x8 af[4], bfr[4];
#pragma unroll
    for (int mb = 0; mb < 4; ++mb)
      af[mb] = *(const bf16x8*)&a_lds[(wr * 64 + mb * 16 + l15) * 32 + quad * 8];
#pragma unroll
    for (int nb = 0; nb < 4; ++nb)
      bfr[nb] = *(const bf16x8*)&b_lds[(wc * 64 + nb * 16 + l15) * 32 + quad * 8];
#pragma unroll
    for (int mb = 0; mb < 4; ++mb)
#pragma unroll
      for (int nb = 0; nb < 4; ++nb)
        acc[mb][nb] = MFMA16(af[mb], bfr[nb], acc[mb][nb]);
    __syncthreads();
  }

#pragma unroll
  for (int mb = 0; mb < 4; ++mb)
#pragma unroll
    for (int nb = 0; nb < 4; ++nb) {
      int row = m0 + wr * 64 + mb * 16 + quad * 4;
      int col = n0 + wc * 64 + nb * 16 + l15;
#pragma unroll
      for (int r = 0; r < 4; ++r)
        C[(size_t)(row + r) * ldc + col] = (CT)acc[mb][nb][r];
    }
}

// ---------------- fused flash-style attention, barrier-free ----------------
// grid (16, 32): q-tile remapped for balance; blockIdx.y = b*16+h. 4 waves,
// wave w owns queries [w*32, w*32+32). NO __syncthreads anywhere:
//  - K fragments loaded global->VGPR (L2-resident, 64B-contiguous per row)
//  - V fragments loaded global->VGPR from pre-transposed vt
//  - P staged in WAVE-PRIVATE swizzled LDS rows (same-wave RAW only)
// Phase 1: QK^T + online (m,l). Phase 2: recompute S, normalize, write attn
// (nontemporal), O += P@V.
__device__ __forceinline__ void qk_tile(const char* kt_base, const bf16x8 (&qf)[2][2],
                                        int l15, int quad, f32x4 (&st)[8][2]) {
  const f32x4 fz = {0.f, 0.f, 0.f, 0.f};
  __builtin_amdgcn_s_setprio(1);
#pragma unroll
  for (int jb = 0; jb < 8; ++jb) {
    const char* kr = kt_base + (size_t)(jb * 16 + l15) * 6144 + quad * 16;
    bf16x8 kf0 = *(const bf16x8*)kr;
    bf16x8 kf1 = *(const bf16x8*)(kr + 64);
    st[jb][0] = MFMA16(kf0, qf[0][0], fz);
    st[jb][0] = MFMA16(kf1, qf[0][1], st[jb][0]);
    st[jb][1] = MFMA16(kf0, qf[1][0], fz);
    st[jb][1] = MFMA16(kf1, qf[1][1], st[jb][1]);
  }
  __builtin_amdgcn_s_setprio(0);
}

__global__ __launch_bounds__(256, 2) void fused_attn(const bf16* __restrict__ qkv,
                                                     const bf16* __restrict__ vt,
                                                     float* __restrict__ attn,
                                                     bf16* __restrict__ o_ws) {
  __shared__ bf16 p_lds[128 * 128];  // [i][j] bf16, 256B rows, XOR-swizzled;
                                     // rows [w*32,w*32+32) are wave-private.

  const int bh = blockIdx.y;
  const int b = bh >> 4, h = bh & 15;
  // balance: pair (bh, bh^16) at equal blockIdx.x gets complementary work
  const int qt = (bh & 16) ? (15 - (int)blockIdx.x) : (int)blockIdx.x;
  const int tid = threadIdx.x;
  const int w = tid >> 6, lane = tid & 63, l15 = lane & 15, quad = lane >> 4;
  const int q0 = qt * 128;

  const char* qkvb = (const char*)qkv;
  const size_t kbyte0 = ((size_t)b * 2048 * 3072 + 1024 + (size_t)h * 64) * 2;
  const char* vtb = (const char*)vt + ((size_t)bh * 64) * 2048 * 2;

  // ---- upper-triangle zero tiles first (overlaps other blocks' compute) ----
  for (int kt = qt + 1; kt < 16; ++kt) {
    float* abase = attn + ((size_t)bh << 22) + (size_t)q0 * 2048 + kt * 128;
    const f32x4 z4 = {0.f, 0.f, 0.f, 0.f};
#pragma unroll
    for (int it = 0; it < 16; ++it) {
      const int il = it * 8 + w * 2 + (lane >> 5);
      __builtin_nontemporal_store(z4, (f32x4*)(abase + (size_t)il * 2048 + (lane & 31) * 4));
    }
  }

  // Q fragments (B-operand), pre-scaled by 1/sqrt(64) (exact in bf16)
  bf16x8 qf[2][2];
#pragma unroll
  for (int ib = 0; ib < 2; ++ib)
#pragma unroll
    for (int ks = 0; ks < 2; ++ks) {
      const bf16* qp = qkv + ((size_t)b * 2048 + q0 + w * 32 + ib * 16 + l15) * 3072
                       + h * 64 + ks * 32 + quad * 8;
      bf16x8 v = *(const bf16x8*)qp;
      bf16x8 sv;
#pragma unroll
      for (int u = 0; u < 8; ++u) sv[u] = (bf16)((float)v[u] * 0.125f);
      qf[ib][ks] = sv;
    }

  float m_run[2] = {-3e38f, -3e38f};
  float l_run[2] = {0.f, 0.f};

  // ---------------- phase 1: row stats (m, l) — pure registers ------------
  for (int kt = 0; kt <= qt; ++kt) {
    f32x4 st[8][2];
    qk_tile(qkvb + kbyte0 + (size_t)kt * 128 * 6144, qf, l15, quad, st);

    const bool diag = (kt == qt);
#pragma unroll
    for (int ib = 0; ib < 2; ++ib) {
      const int ig = q0 + w * 32 + ib * 16 + l15;
      float tmax = -3e38f;
#pragma unroll
      for (int jb = 0; jb < 8; ++jb)
#pragma unroll
        for (int r = 0; r < 4; ++r) {
          const int jg = kt * 128 + jb * 16 + quad * 4 + r;
          float s = st[jb][ib][r];
          if (diag && jg > ig) { s = -3e38f; st[jb][ib][r] = s; }
          tmax = fmaxf(tmax, s);
        }
      tmax = fmaxf(tmax, __shfl_xor(tmax, 16));
      tmax = fmaxf(tmax, __shfl_xor(tmax, 32));
      const float mnew = fmaxf(m_run[ib], tmax);
      float tsum = 0.f;
#pragma unroll
      for (int jb = 0; jb < 8; ++jb)
#pragma unroll
        for (int r = 0; r < 4; ++r) {
          const float s = st[jb][ib][r];
          tsum += (s > -1e38f) ? __expf(s - mnew) : 0.f;
        }
      tsum += __shfl_xor(tsum, 16);
      tsum += __shfl_xor(tsum, 32);
      l_run[ib] = l_run[ib] * __expf(m_run[ib] - mnew) + tsum;
      m_run[ib] = mnew;
    }
  }

  const float invl[2] = {1.f / l_run[0], 1.f / l_run[1]};

  f32x4 oacc[2][4];
#pragma unroll
  for (int ib = 0; ib < 2; ++ib)
#pragma unroll
    for (int db = 0; db < 4; ++db) {
      const f32x4 fz = {0.f, 0.f, 0.f, 0.f};
      oacc[ib][db] = fz;
    }

  // ---------------- phase 2: normalize, attn write, PV — barrier-free -----
  for (int kt = 0; kt <= qt; ++kt) {
    f32x4 st[8][2];
    qk_tile(qkvb + kbyte0 + (size_t)kt * 128 * 6144, qf, l15, quad, st);

    const bool diag = (kt == qt);
    // pack normalized P (bf16) into wave-private swizzled LDS rows
#pragma unroll
    for (int ib = 0; ib < 2; ++ib) {
      const int ig = q0 + w * 32 + ib * 16 + l15;
      const int il = w * 32 + ib * 16 + l15;
#pragma unroll
      for (int jb = 0; jb < 8; ++jb) {
        bf16x4 pk;
#pragma unroll
        for (int r = 0; r < 4; ++r) {
          const int jg = kt * 128 + jb * 16 + quad * 4 + r;
          float p = __expf(st[jb][ib][r] - m_run[ib]) * invl[ib];
          if (diag && jg > ig) p = 0.f;
          pk[r] = (bf16)p;
        }
        *(bf16x4*)((char*)p_lds + il * 256 + ((jb * 32 + quad * 8) ^ ((il & 7) << 4))) = pk;
      }
    }

    // issue V fragment loads early (st dead now; latency hides under attn write)
    bf16x8 vfr[4][4];
#pragma unroll
    for (int js = 0; js < 4; ++js)
#pragma unroll
      for (int db = 0; db < 4; ++db) {
        const int dl = db * 16 + l15;
        vfr[js][db] = *(const bf16x8*)(vtb + (size_t)dl * 4096 + kt * 256 + js * 64 + quad * 16);
      }

    // attn tile write: wave-local rows, coalesced, nontemporal
    {
      float* abase = attn + ((size_t)bh << 22) + (size_t)q0 * 2048 + kt * 128;
#pragma unroll
      for (int it = 0; it < 16; ++it) {
        const int il = w * 32 + it * 2 + (lane >> 5);
        const int jb4 = (lane & 31) * 8;
        bf16x4 pv = *(const bf16x4*)((char*)p_lds + il * 256 + (jb4 ^ ((il & 7) << 4)));
        f32x4 f = {(float)pv[0], (float)pv[1], (float)pv[2], (float)pv[3]};
        __builtin_nontemporal_store(f, (f32x4*)(abase + (size_t)il * 2048 + (lane & 31) * 4));
      }
    }

    // O += P @ V (P from wave-private LDS, V from registers)
    __builtin_amdgcn_s_setprio(1);
#pragma unroll
    for (int js = 0; js < 4; ++js) {
      bf16x8 pa[2];
#pragma unroll
      for (int ib = 0; ib < 2; ++ib) {
        const int il = w * 32 + ib * 16 + l15;
        pa[ib] = *(const bf16x8*)((char*)p_lds + il * 256 + ((js * 64 + quad * 16) ^ ((il & 7) << 4)));
      }
#pragma unroll
      for (int ib = 0; ib < 2; ++ib)
#pragma unroll
        for (int db = 0; db < 4; ++db)
          oacc[ib][db] = MFMA16(pa[ib], vfr[js][db], oacc[ib][db]);
    }
    __builtin_amdgcn_s_setprio(0);
  }

  // write O (bf16) for the out-projection GEMM
#pragma unroll
  for (int ib = 0; ib < 2; ++ib)
#pragma unroll
    for (int db = 0; db < 4; ++db)
#pragma unroll
      for (int r = 0; r < 4; ++r) {
        const int ig = q0 + w * 32 + ib * 16 + quad * 4 + r;
        const int dg = h * 64 + db * 16 + l15;
        o_ws[((size_t)b * 2048 + ig) * 1024 + dg] = (bf16)oacc[ib][db][r];
      }
}

// ---------------- launch ----------------------------------------------------
extern "C" void kernel_launch(void* const* d_in, const int* in_sizes, int n_in,
                              void* d_out, int out_size, void* d_ws, size_t ws_size,
                              hipStream_t stream) {
  const void* x_raw = d_in[0];  // [2,2048,1024] fp32
  const void* w_qkv = d_in[1];  // [1024,3072]   fp32
  const void* w_out = d_in[2];  // [1024,1024]   fp32
  float* out  = (float*)d_out;               // [2,2048,1024] fp32
  float* attn = out + 4194304;               // [2,16,2048,2048] fp32

  // workspace layout (bf16 elements), 40 MB + flag:
  //   qkv_ws [0, 12582912)                      : qkv bf16 [4096][3072]
  //   R1     [12582912, 16777216) (4.19M elems) : x_bf -> vt_ws -> woT
  //   R2     [16777216, 20971520) (4.19M elems) : wqkvT -> o_ws
  bf16* ws     = (bf16*)d_ws;
  bf16* qkv_ws = ws;
  bf16* x_bf   = ws + 12582912;
  bf16* vt_ws  = ws + 12582912;  // overwrites x_bf after qkv GEMM (dead)
  bf16* woT    = ws + 12582912;  // overwrites vt after fused_attn (dead)
  bf16* wqkvT  = ws + 16777216;
  bf16* o_ws   = ws + 16777216;  // overwrites wqkvT after qkv GEMM (dead)
  int*  flag   = (int*)(ws + 20971520);

  detect_dtype<<<1, 256, 0, stream>>>((const unsigned short*)w_qkv, flag);
  convert_to_bf16<<<2048, 256, 0, stream>>>(x_raw, x_bf, flag);
  transpose_any<<<dim3(48, 16), 256, 0, stream>>>(w_qkv, wqkvT, flag, 1024, 3072);
  // qkv = x @ W_qkv : [4096][3072] bf16
  gemm_bt<bf16><<<dim3(24, 32), 256, 0, stream>>>(x_bf, wqkvT, qkv_ws, 1024, 3072);
  // vt[bh][d][j] = V^T per head
  transpose_v<<<dim3(32, 32), 256, 0, stream>>>(qkv_ws, vt_ws);
  // fused: attn (fp32, normalized, causal-masked) + O = P@V (bf16)
  fused_attn<<<dim3(16, 32), 256, 0, stream>>>(qkv_ws, vt_ws, attn, o_ws);
  // W_out^T (re-transposed here so it can live in R1 after vt dies)
  transpose_any<<<dim3(16, 16), 256, 0, stream>>>(w_out, woT, flag, 1024, 1024);
  // out = o @ W_out  (fp32 out)
  gemm_bt<float><<<dim3(8, 32), 256, 0, stream>>>(o_ws, woT, out, 1024, 1024);
}

// Round 5
// 693.546 us; speedup vs baseline: 1.0723x; 1.0723x over previous
//
#include <hip/hip_runtime.h>
#include <hip/hip_bf16.h>

typedef __bf16 bf16;
typedef __bf16 bf16x4 __attribute__((ext_vector_type(4)));
typedef __bf16 bf16x8 __attribute__((ext_vector_type(8)));
typedef float  f32x4  __attribute__((ext_vector_type(4)));

#define MFMA16(a, b, c) __builtin_amdgcn_mfma_f32_16x16x32_bf16((a), (b), (c), 0, 0, 0)

typedef const __attribute__((address_space(1))) void* gptr_t;
typedef __attribute__((address_space(3))) void* sptr_t;

__device__ __forceinline__ void load_lds16(const bf16* g, bf16* l) {
  __builtin_amdgcn_global_load_lds((gptr_t)g, (sptr_t)l, 16, 0, 0);
}

// ---------------- input dtype detector -------------------------------------
__global__ __launch_bounds__(256) void detect_dtype(const unsigned short* __restrict__ w,
                                                    int* __restrict__ flag) {
  __shared__ int cnt[256];
  int c = 0;
#pragma unroll
  for (int k = 0; k < 16; ++k) {
    unsigned short v = w[(threadIdx.x * 16 + k) * 2];
    int e = (v >> 7) & 0xFF;
    c += (e >= 90 && e <= 130) ? 1 : 0;
  }
  cnt[threadIdx.x] = c;
  __syncthreads();
  if (threadIdx.x == 0) {
    int t = 0;
    for (int i = 0; i < 256; ++i) t += cnt[i];
    *flag = (t > 2048) ? 1 : 0;
  }
}

// ---------------- convert x -> bf16 (either source dtype) ------------------
__global__ __launch_bounds__(256) void convert_to_bf16(const void* __restrict__ in,
                                                       bf16* __restrict__ out,
                                                       const int* __restrict__ flag) {
  const int i0 = (blockIdx.x * 256 + threadIdx.x) * 8;
  if (*flag) {
    *(bf16x8*)(out + i0) = *(const bf16x8*)((const bf16*)in + i0);
  } else {
    const float* p = (const float*)in;
    float4 a = *(const float4*)(p + i0);
    float4 b = *(const float4*)(p + i0 + 4);
    bf16x8 v;
    v[0] = (bf16)a.x; v[1] = (bf16)a.y; v[2] = (bf16)a.z; v[3] = (bf16)a.w;
    v[4] = (bf16)b.x; v[5] = (bf16)b.y; v[6] = (bf16)b.z; v[7] = (bf16)b.w;
    *(bf16x8*)(out + i0) = v;
  }
}

// ---------------- transpose+convert: in [R][C] -> out [C][R] bf16 ----------
__global__ __launch_bounds__(256) void transpose_any(const void* __restrict__ in,
                                                     bf16* __restrict__ out,
                                                     const int* __restrict__ flag,
                                                     int R, int C) {
  __shared__ bf16 t[64][65];
  const int c0 = blockIdx.x * 64, r0 = blockIdx.y * 64;
  const int tid = threadIdx.x;
  const int lc = tid & 63, lr4 = tid >> 6;
  if (*flag) {
    const bf16* p = (const bf16*)in;
#pragma unroll
    for (int i = 0; i < 16; ++i) {
      int r = i * 4 + lr4;
      t[r][lc] = p[(size_t)(r0 + r) * C + c0 + lc];
    }
  } else {
    const float* p = (const float*)in;
#pragma unroll
    for (int i = 0; i < 16; ++i) {
      int r = i * 4 + lr4;
      t[r][lc] = (bf16)p[(size_t)(r0 + r) * C + c0 + lc];
    }
  }
  __syncthreads();
#pragma unroll
  for (int i = 0; i < 16; ++i) {
    int r = i * 4 + lr4;
    out[(size_t)(c0 + r) * R + r0 + lc] = t[lc][r];
  }
}

// ---------------- V^T: qkv[b][j][2048 + h*64 + d] -> vt[bh][d][j] ----------
__global__ __launch_bounds__(256) void transpose_v(const bf16* __restrict__ qkv,
                                                   bf16* __restrict__ vt) {
  __shared__ bf16 t[64][65];
  const int bh = blockIdx.y, b = bh >> 4, h = bh & 15;
  const int j0 = blockIdx.x * 64;
  const int tid = threadIdx.x;
  const int lc = tid & 63, lr4 = tid >> 6;
  const bf16* src = qkv + (size_t)b * 2048 * 3072 + 2048 + (size_t)h * 64;
#pragma unroll
  for (int i = 0; i < 16; ++i) {
    int j = i * 4 + lr4;
    t[j][lc] = src[(size_t)(j0 + j) * 3072 + lc];
  }
  __syncthreads();
  bf16* dst = vt + (size_t)bh * 64 * 2048;
#pragma unroll
  for (int i = 0; i < 16; ++i) {
    int d = i * 4 + lr4;
    dst[(size_t)d * 2048 + j0 + lc] = t[lc][d];
  }
}

// ---------------- GEMM: C[M][N] = A[M][K] * Bt[N][K]^T, bf16 in, CT out ----
template <typename CT>
__global__ __launch_bounds__(256) void gemm_bt(const bf16* __restrict__ A,
                                               const bf16* __restrict__ Bt,
                                               CT* __restrict__ C,
                                               int K, int ldc) {
  __shared__ bf16 a_lds[128 * 32];
  __shared__ bf16 b_lds[128 * 32];
  const int tid = threadIdx.x;
  const int w = tid >> 6, lane = tid & 63, l15 = lane & 15, quad = lane >> 4;
  const int wr = w >> 1, wc = w & 1;
  const int m0 = blockIdx.y * 128, n0 = blockIdx.x * 128;

  const f32x4 fz = {0.f, 0.f, 0.f, 0.f};
  f32x4 acc[4][4];
#pragma unroll
  for (int i = 0; i < 4; ++i)
#pragma unroll
    for (int j = 0; j < 4; ++j) acc[i][j] = fz;

  for (int k0 = 0; k0 < K; k0 += 32) {
#pragma unroll
    for (int i = 0; i < 2; ++i) {
      int c = tid + i * 256;
      int r = c >> 2, kk = c & 3;
      load_lds16(A + (size_t)(m0 + r) * K + k0 + kk * 8, &a_lds[c * 8]);
      load_lds16(Bt + (size_t)(n0 + r) * K + k0 + kk * 8, &b_lds[c * 8]);
    }
    __syncthreads();
    bf16x8 af[4], bfr[4];
#pragma unroll
    for (int mb = 0; mb < 4; ++mb)
      af[mb] = *(const bf16x8*)&a_lds[(wr * 64 + mb * 16 + l15) * 32 + quad * 8];
#pragma unroll
    for (int nb = 0; nb < 4; ++nb)
      bfr[nb] = *(const bf16x8*)&b_lds[(wc * 64 + nb * 16 + l15) * 32 + quad * 8];
#pragma unroll
    for (int mb = 0; mb < 4; ++mb)
#pragma unroll
      for (int nb = 0; nb < 4; ++nb)
        acc[mb][nb] = MFMA16(af[mb], bfr[nb], acc[mb][nb]);
    __syncthreads();
  }

#pragma unroll
  for (int mb = 0; mb < 4; ++mb)
#pragma unroll
    for (int nb = 0; nb < 4; ++nb) {
      int row = m0 + wr * 64 + mb * 16 + quad * 4;
      int col = n0 + wc * 64 + nb * 16 + l15;
#pragma unroll
      for (int r = 0; r < 4; ++r)
        C[(size_t)(row + r) * ldc + col] = (CT)acc[mb][nb][r];
    }
}

// ---------------- fused flash-style attention -------------------------------
// grid (16, 32): q-tile remapped for balance; blockIdx.y = b*16+h. 4 waves,
// wave w owns queries [w*32, w*32+32).
//  - K staged via global_load_lds, double-buffered (1 barrier / iteration)
//  - V loaded global->VGPR from pre-transposed vt (issued early, used late)
//  - P staged in WAVE-PRIVATE swizzled LDS rows (same-wave RAW, no barrier)
//  - zero upper-triangle tiles interleaved 1-per-iteration across BOTH phases
//    (spreads the mandatory 537 MB of zero writes over the whole kernel)
//  - attn stores nontemporal (1.07 GB stream, never re-read)
__device__ __forceinline__ void compute_st(const bf16* k_lds, const bf16x8 (&qf)[2][2],
                                           int l15, int quad, f32x4 (&st)[8][2]) {
  const f32x4 fz = {0.f, 0.f, 0.f, 0.f};
  __builtin_amdgcn_s_setprio(1);
#pragma unroll
  for (int jb = 0; jb < 8; ++jb) {
    const int jl = jb * 16 + l15;
    const char* kb = (const char*)k_lds + jl * 128;
    const int sw = (jl & 7) << 4;
    bf16x8 kf0 = *(const bf16x8*)(kb + ((quad * 16) ^ sw));
    bf16x8 kf1 = *(const bf16x8*)(kb + ((64 + quad * 16) ^ sw));
    st[jb][0] = MFMA16(kf0, qf[0][0], fz);
    st[jb][0] = MFMA16(kf1, qf[0][1], st[jb][0]);
    st[jb][1] = MFMA16(kf0, qf[1][0], fz);
    st[jb][1] = MFMA16(kf1, qf[1][1], st[jb][1]);
  }
  __builtin_amdgcn_s_setprio(0);
}

__global__ __launch_bounds__(256, 2) void fused_attn(const bf16* __restrict__ qkv,
                                                     const bf16* __restrict__ vt,
                                                     float* __restrict__ attn,
                                                     bf16* __restrict__ o_ws) {
  __shared__ bf16 k_lds[2][128 * 64];  // [j][d], rows XOR-swizzled, 128B rows
  __shared__ bf16 p_lds[128 * 128];    // [i][j], 256B rows, XOR-swizzled;
                                       // rows [w*32,w*32+32) wave-private.

  const int bh = blockIdx.y;
  const int b = bh >> 4, h = bh & 15;
  // balance: pair (bh, bh^16) at equal blockIdx.x gets complementary work
  const int qt = (bh & 16) ? (15 - (int)blockIdx.x) : (int)blockIdx.x;
  const int tid = threadIdx.x;
  const int w = tid >> 6, lane = tid & 63, l15 = lane & 15, quad = lane >> 4;
  const int q0 = qt * 128;

  const char* qkvb = (const char*)qkv;
  const size_t kbyte0 = ((size_t)b * 2048 * 3072 + 1024 + (size_t)h * 64) * 2;
  const char* vtb = (const char*)vt + ((size_t)bh * 64) * 2048 * 2;
  float* attn_q0 = attn + ((size_t)bh << 22) + (size_t)q0 * 2048;

  // zero-tile writer: one 128x128 fp32 zero tile, coalesced, nontemporal
  int zt = qt + 1;
  auto zero_tile_at = [&](int t) {
    float* abase = attn_q0 + t * 128;
    const f32x4 z4 = {0.f, 0.f, 0.f, 0.f};
#pragma unroll
    for (int it = 0; it < 16; ++it) {
      const int il = it * 8 + w * 2 + (lane >> 5);
      __builtin_nontemporal_store(z4, (f32x4*)(abase + (size_t)il * 2048 + (lane & 31) * 4));
    }
  };

  // staging: pre-swizzled global source, linear LDS dest (rule #21)
  auto stage_k = [&](int kt, int buf) {
#pragma unroll
    for (int c = 0; c < 4; ++c) {
      const int L = c * 4096 + tid * 16;
      const int j = L >> 7, cb = L & 127;
      const char* src = qkvb + kbyte0 + (size_t)(kt * 128 + j) * 6144 + (cb ^ ((j & 7) << 4));
      load_lds16((const bf16*)src, (bf16*)((char*)k_lds[buf] + L));
    }
  };

  // Q fragments (B-operand), pre-scaled by 1/sqrt(64) (exact in bf16)
  bf16x8 qf[2][2];
#pragma unroll
  for (int ib = 0; ib < 2; ++ib)
#pragma unroll
    for (int ks = 0; ks < 2; ++ks) {
      const bf16* qp = qkv + ((size_t)b * 2048 + q0 + w * 32 + ib * 16 + l15) * 3072
                       + h * 64 + ks * 32 + quad * 8;
      bf16x8 v = *(const bf16x8*)qp;
      bf16x8 sv;
#pragma unroll
      for (int u = 0; u < 8; ++u) sv[u] = (bf16)((float)v[u] * 0.125f);
      qf[ib][ks] = sv;
    }

  float m_run[2] = {-3e38f, -3e38f};
  float l_run[2] = {0.f, 0.f};

  // ---------------- phase 1: row stats (m, l), K dbuf ----------------------
  stage_k(0, 0);
  __syncthreads();
  for (int kt = 0; kt <= qt; ++kt) {
    if (kt < qt) stage_k(kt + 1, (kt + 1) & 1);
    if (zt < 16) zero_tile_at(zt++);

    f32x4 st[8][2];
    compute_st(k_lds[kt & 1], qf, l15, quad, st);

    const bool diag = (kt == qt);
#pragma unroll
    for (int ib = 0; ib < 2; ++ib) {
      const int ig = q0 + w * 32 + ib * 16 + l15;
      float tmax = -3e38f;
#pragma unroll
      for (int jb = 0; jb < 8; ++jb)
#pragma unroll
        for (int r = 0; r < 4; ++r) {
          const int jg = kt * 128 + jb * 16 + quad * 4 + r;
          float s = st[jb][ib][r];
          if (diag && jg > ig) { s = -3e38f; st[jb][ib][r] = s; }
          tmax = fmaxf(tmax, s);
        }
      tmax = fmaxf(tmax, __shfl_xor(tmax, 16));
      tmax = fmaxf(tmax, __shfl_xor(tmax, 32));
      const float mnew = fmaxf(m_run[ib], tmax);
      float tsum = 0.f;
#pragma unroll
      for (int jb = 0; jb < 8; ++jb)
#pragma unroll
        for (int r = 0; r < 4; ++r) {
          const float s = st[jb][ib][r];
          tsum += (s > -1e38f) ? __expf(s - mnew) : 0.f;
        }
      tsum += __shfl_xor(tsum, 16);
      tsum += __shfl_xor(tsum, 32);
      l_run[ib] = l_run[ib] * __expf(m_run[ib] - mnew) + tsum;
      m_run[ib] = mnew;
    }
    __syncthreads();  // drains K(kt+1) staging; guards k_lds reuse
  }

  const float invl[2] = {1.f / l_run[0], 1.f / l_run[1]};

  f32x4 oacc[2][4];
#pragma unroll
  for (int ib = 0; ib < 2; ++ib)
#pragma unroll
    for (int db = 0; db < 4; ++db) {
      const f32x4 fz = {0.f, 0.f, 0.f, 0.f};
      oacc[ib][db] = fz;
    }

  // ------- phase 2: P write + PV; K dbuf, V->VGPR, 1 barrier/iter ---------
  stage_k(0, 0);
  __syncthreads();
  for (int kt = 0; kt <= qt; ++kt) {
    if (kt < qt) stage_k(kt + 1, (kt + 1) & 1);
    if (zt < 16) zero_tile_at(zt++);

    f32x4 st[8][2];
    compute_st(k_lds[kt & 1], qf, l15, quad, st);

    const bool diag = (kt == qt);
    // pack normalized P (bf16) into wave-private swizzled LDS rows
#pragma unroll
    for (int ib = 0; ib < 2; ++ib) {
      const int ig = q0 + w * 32 + ib * 16 + l15;
      const int il = w * 32 + ib * 16 + l15;
#pragma unroll
      for (int jb = 0; jb < 8; ++jb) {
        bf16x4 pk;
#pragma unroll
        for (int r = 0; r < 4; ++r) {
          const int jg = kt * 128 + jb * 16 + quad * 4 + r;
          float p = __expf(st[jb][ib][r] - m_run[ib]) * invl[ib];
          if (diag && jg > ig) p = 0.f;
          pk[r] = (bf16)p;
        }
        *(bf16x4*)((char*)p_lds + il * 256 + ((jb * 32 + quad * 8) ^ ((il & 7) << 4))) = pk;
      }
    }

    // V fragments from global (issued now, consumed after the attn write)
    bf16x8 vfr[4][4];
#pragma unroll
    for (int js = 0; js < 4; ++js)
#pragma unroll
      for (int db = 0; db < 4; ++db) {
        const int dl = db * 16 + l15;
        vfr[js][db] = *(const bf16x8*)(vtb + (size_t)dl * 4096 + kt * 256 + js * 64 + quad * 16);
      }

    // attn tile write: own-wave rows, coalesced, nontemporal
    {
      float* abase = attn_q0 + kt * 128;
#pragma unroll
      for (int it = 0; it < 16; ++it) {
        const int il = w * 32 + it * 2 + (lane >> 5);
        const int jb4 = (lane & 31) * 8;
        bf16x4 pv = *(const bf16x4*)((char*)p_lds + il * 256 + (jb4 ^ ((il & 7) << 4)));
        f32x4 f = {(float)pv[0], (float)pv[1], (float)pv[2], (float)pv[3]};
        __builtin_nontemporal_store(f, (f32x4*)(abase + (size_t)il * 2048 + (lane & 31) * 4));
      }
    }

    // O += P @ V (P from own-wave LDS rows, V from registers)
    __builtin_amdgcn_s_setprio(1);
#pragma unroll
    for (int js = 0; js < 4; ++js) {
      bf16x8 pa[2];
#pragma unroll
      for (int ib = 0; ib < 2; ++ib) {
        const int il = w * 32 + ib * 16 + l15;
        pa[ib] = *(const bf16x8*)((char*)p_lds + il * 256 + ((js * 64 + quad * 16) ^ ((il & 7) << 4)));
      }
#pragma unroll
      for (int ib = 0; ib < 2; ++ib)
#pragma unroll
        for (int db = 0; db < 4; ++db)
          oacc[ib][db] = MFMA16(pa[ib], vfr[js][db], oacc[ib][db]);
    }
    __builtin_amdgcn_s_setprio(0);
    __syncthreads();  // drains K(kt+1); k_lds reads done before next stage
  }

  // flush any remaining zero tiles (small-qt blocks)
  while (zt < 16) zero_tile_at(zt++);

  // write O (bf16) for the out-projection GEMM
#pragma unroll
  for (int ib = 0; ib < 2; ++ib)
#pragma unroll
    for (int db = 0; db < 4; ++db)
#pragma unroll
      for (int r = 0; r < 4; ++r) {
        const int ig = q0 + w * 32 + ib * 16 + quad * 4 + r;
        const int dg = h * 64 + db * 16 + l15;
        o_ws[((size_t)b * 2048 + ig) * 1024 + dg] = (bf16)oacc[ib][db][r];
      }
}

// ---------------- launch ----------------------------------------------------
extern "C" void kernel_launch(void* const* d_in, const int* in_sizes, int n_in,
                              void* d_out, int out_size, void* d_ws, size_t ws_size,
                              hipStream_t stream) {
  const void* x_raw = d_in[0];  // [2,2048,1024] fp32
  const void* w_qkv = d_in[1];  // [1024,3072]   fp32
  const void* w_out = d_in[2];  // [1024,1024]   fp32
  float* out  = (float*)d_out;               // [2,2048,1024] fp32
  float* attn = out + 4194304;               // [2,16,2048,2048] fp32

  // workspace layout (bf16 elements), 40 MB + flag:
  //   qkv_ws [0, 12582912)                      : qkv bf16 [4096][3072]
  //   R1     [12582912, 16777216) (4.19M elems) : x_bf -> vt_ws -> woT
  //   R2     [16777216, 20971520) (4.19M elems) : wqkvT -> o_ws
  bf16* ws     = (bf16*)d_ws;
  bf16* qkv_ws = ws;
  bf16* x_bf   = ws + 12582912;
  bf16* vt_ws  = ws + 12582912;  // overwrites x_bf after qkv GEMM (dead)
  bf16* woT    = ws + 12582912;  // overwrites vt after fused_attn (dead)
  bf16* wqkvT  = ws + 16777216;
  bf16* o_ws   = ws + 16777216;  // overwrites wqkvT after qkv GEMM (dead)
  int*  flag   = (int*)(ws + 20971520);

  detect_dtype<<<1, 256, 0, stream>>>((const unsigned short*)w_qkv, flag);
  convert_to_bf16<<<2048, 256, 0, stream>>>(x_raw, x_bf, flag);
  transpose_any<<<dim3(48, 16), 256, 0, stream>>>(w_qkv, wqkvT, flag, 1024, 3072);
  // qkv = x @ W_qkv : [4096][3072] bf16
  gemm_bt<bf16><<<dim3(24, 32), 256, 0, stream>>>(x_bf, wqkvT, qkv_ws, 1024, 3072);
  // vt[bh][d][j] = V^T per head
  transpose_v<<<dim3(32, 32), 256, 0, stream>>>(qkv_ws, vt_ws);
  // fused: attn (fp32, normalized, causal-masked) + O = P@V (bf16)
  fused_attn<<<dim3(16, 32), 256, 0, stream>>>(qkv_ws, vt_ws, attn, o_ws);
  // W_out^T (re-transposed here so it can live in R1 after vt dies)
  transpose_any<<<dim3(16, 16), 256, 0, stream>>>(w_out, woT, flag, 1024, 1024);
  // out = o @ W_out  (fp32 out)
  gemm_bt<float><<<dim3(8, 32), 256, 0, stream>>>(o_ws, woT, out, 1024, 1024);
}